// Round 2
// baseline (6871.277 us; speedup 1.0000x reference)
//
#include <hip/hip_runtime.h>
#include <stdint.h>

#define NU 200000
#define NI 100000
#define DD 64
#define NE 1000000
#define EPSV 0.1f
#define NBUCK 65536
#define CEILDIV(a,b) (((a)+(b)-1)/(b))

// ---------------------------------------------------------------------------
// Threefry-2x32 (20 rounds), matches jax._src.prng.threefry2x32 exactly.
// ---------------------------------------------------------------------------
__host__ __device__ inline void tf2x32(uint32_t k0, uint32_t k1,
                                       uint32_t x0, uint32_t x1,
                                       uint32_t &o0, uint32_t &o1) {
  uint32_t ks0 = k0, ks1 = k1, ks2 = k0 ^ k1 ^ 0x1BD11BDAu;
  x0 += ks0; x1 += ks1;
#define TF_RND(r) { x0 += x1; x1 = (x1 << (r)) | (x1 >> (32 - (r))); x1 ^= x0; }
  TF_RND(13) TF_RND(15) TF_RND(26) TF_RND(6)   x0 += ks1; x1 += ks2 + 1u;
  TF_RND(17) TF_RND(29) TF_RND(16) TF_RND(24)  x0 += ks2; x1 += ks0 + 2u;
  TF_RND(13) TF_RND(15) TF_RND(26) TF_RND(6)   x0 += ks0; x1 += ks1 + 3u;
  TF_RND(17) TF_RND(29) TF_RND(16) TF_RND(24)  x0 += ks1; x1 += ks2 + 4u;
  TF_RND(13) TF_RND(15) TF_RND(26) TF_RND(6)   x0 += ks2; x1 += ks0 + 5u;
#undef TF_RND
  o0 = x0; o1 = x1;
}

struct K2 { uint32_t a, b; };
static inline K2 h_tf(K2 k, uint32_t x0, uint32_t x1) {
  K2 r; tf2x32(k.a, k.b, x0, x1, r.a, r.b); return r;
}
// partitionable semantics: split -> key_j = tf(k, hi=0, lo=j); fold_in(d) = tf(k, 0, d).

// ---------------------------------------------------------------------------
// Edge cosine weights. 16 lanes per edge, float4 per lane.
// ---------------------------------------------------------------------------
__global__ void k_edge(const int* __restrict__ u_id, const int* __restrict__ i_id,
                       const int* __restrict__ T, const float* __restrict__ betap,
                       const float* __restrict__ UE, const float* __restrict__ IE,
                       const float* __restrict__ W0, const float* __restrict__ W1,
                       float* __restrict__ s)
{
  int g = blockIdx.x * blockDim.x + threadIdx.x;
  int e = g >> 4, lane = g & 15;
  if (e >= NE) return;
  int u = u_id[e], it = i_id[e];
  float4 a = ((const float4*)UE)[u * 16 + lane];
  float4 b = ((const float4*)IE)[it * 16 + lane];
  float4 t;
  if (lane < 8) t = ((const float4*)W0)[T[2 * e] * 8 + lane];
  else          t = ((const float4*)W1)[T[2 * e + 1] * 8 + (lane - 8)];
  float ux = a.x + t.x, uy = a.y + t.y, uz = a.z + t.z, uw = a.w + t.w;
  float ix = b.x + t.x, iy = b.y + t.y, iz = b.z + t.z, iw = b.w + t.w;
  float uu = ux * ux + uy * uy + uz * uz + uw * uw;
  float ii = ix * ix + iy * iy + iz * iz + iw * iw;
  float ui = ux * ix + uy * iy + uz * iz + uw * iw;
#pragma unroll
  for (int m = 1; m < 16; m <<= 1) {
    uu += __shfl_xor(uu, m);
    ii += __shfl_xor(ii, m);
    ui += __shfl_xor(ui, m);
  }
  if (lane == 0) {
    float c = ui / (fmaxf(sqrtf(uu), 1e-12f) * fmaxf(sqrtf(ii), 1e-12f));
    float sv = (c + 1.0f) * 0.5f;
    s[e] = (sv < betap[0]) ? 0.0f : sv;
  }
}

// ---------------------------------------------------------------------------
// CSR build
// ---------------------------------------------------------------------------
__global__ void k_count(const int* __restrict__ u_id, const int* __restrict__ i_id,
                        int* __restrict__ cnt_u, int* __restrict__ cnt_i)
{
  int e = blockIdx.x * blockDim.x + threadIdx.x;
  if (e < NE) {
    atomicAdd(&cnt_u[u_id[e]], 1);
    atomicAdd(&cnt_i[i_id[e]], 1);
  }
}

// single-block exclusive scan; writes ptr[0..n] and a cursor copy.
// NOTE: cursor may legally alias cnt (we read cnt[i] before writing
// cursor[i]) — therefore NO __restrict__ on these parameters.
__global__ void k_scan(const int* cnt, int* ptr, int* cursor, int n)
{
  __shared__ int part[1024];
  int tid = threadIdx.x;
  int chunk = (n + 1023) >> 10;
  int s0 = tid * chunk;
  int e0 = s0 + chunk; if (e0 > n) e0 = n;
  int sum = 0;
  for (int i = s0; i < e0; ++i) sum += cnt[i];
  part[tid] = sum;
  __syncthreads();
  for (int off = 1; off < 1024; off <<= 1) {
    int v = (tid >= off) ? part[tid - off] : 0;
    __syncthreads();
    part[tid] += v;
    __syncthreads();
  }
  int excl = (tid == 0) ? 0 : part[tid - 1];
  if (tid == 1023) ptr[n] = part[1023];
  for (int i = s0; i < e0; ++i) {
    int c = cnt[i];
    ptr[i] = excl;
    cursor[i] = excl;
    excl += c;
  }
}

__global__ void k_scatter_csr(const int* __restrict__ u_id, const int* __restrict__ i_id,
                              const float* __restrict__ s,
                              int* __restrict__ cur_u, int* __restrict__ cur_i,
                              int* __restrict__ col_u, float* __restrict__ w_u,
                              int* __restrict__ col_i, float* __restrict__ w_i)
{
  int e = blockIdx.x * blockDim.x + threadIdx.x;
  if (e < NE) {
    float w = s[e];
    int pu = atomicAdd(&cur_u[u_id[e]], 1);
    col_u[pu] = i_id[e]; w_u[pu] = w;
    int pi = atomicAdd(&cur_i[i_id[e]], 1);
    col_i[pi] = u_id[e]; w_i[pi] = w;
  }
}

// ---------------------------------------------------------------------------
// SpMM with fused layer-mean accumulation:
//   Y[r]   = sum_k w[k] * X[col[k]]          (16 lanes per row, float4/lane)
//   if acc: acc[r] = (first ? Y[r] : acc[r]+Y[r]) * scale
// Deterministic per row (sequential), no atomics, no zero-init needed.
// ---------------------------------------------------------------------------
__global__ void k_spmm(const int* __restrict__ ptr, const int* __restrict__ col,
                       const float* __restrict__ w, const float* __restrict__ X,
                       float* __restrict__ Y, float* __restrict__ acc,
                       int nrows, int first, float scale)
{
  int g = blockIdx.x * blockDim.x + threadIdx.x;
  int r = g >> 4, lane = g & 15;
  if (r >= nrows) return;
  int b = ptr[r], e2 = ptr[r + 1];
  float4 a = make_float4(0.f, 0.f, 0.f, 0.f);
  for (int k = b; k < e2; ++k) {
    float wk = w[k];
    int c = col[k];
    float4 x = ((const float4*)X)[c * 16 + lane];
    a.x += wk * x.x; a.y += wk * x.y; a.z += wk * x.z; a.w += wk * x.w;
  }
  ((float4*)Y)[r * 16 + lane] = a;
  if (acc) {
    float4 v;
    if (first) v = a;
    else {
      v = ((const float4*)acc)[r * 16 + lane];
      v.x += a.x; v.y += a.y; v.z += a.z; v.w += a.w;
    }
    v.x *= scale; v.y *= scale; v.z *= scale; v.w *= scale;
    ((float4*)acc)[r * 16 + lane] = v;
  }
}

// O[r] = S[r] + EPS * l2norm(S[perm[r]]);  acc = (first ? O : acc+O) * scale
__global__ void k_noise(const float* __restrict__ S, const int* __restrict__ perm,
                        float* __restrict__ O, float* __restrict__ acc,
                        int nrows, int first, float scale)
{
  int g = blockIdx.x * blockDim.x + threadIdx.x;
  int r = g >> 4, lane = g & 15;
  if (r >= nrows) return;
  int pr = perm[r];
  float4 z = ((const float4*)S)[pr * 16 + lane];
  float ss = z.x * z.x + z.y * z.y + z.z * z.z + z.w * z.w;
#pragma unroll
  for (int m = 1; m < 16; m <<= 1) ss += __shfl_xor(ss, m);
  float coef = EPSV / fmaxf(sqrtf(ss), 1e-12f);
  float4 v = ((const float4*)S)[r * 16 + lane];
  v.x += coef * z.x; v.y += coef * z.y; v.z += coef * z.z; v.w += coef * z.w;
  ((float4*)O)[r * 16 + lane] = v;
  float4 a;
  if (first) a = v;
  else {
    a = ((const float4*)acc)[r * 16 + lane];
    a.x += v.x; a.y += v.y; a.z += v.z; a.w += v.w;
  }
  a.x *= scale; a.y *= scale; a.z *= scale; a.w *= scale;
  ((float4*)acc)[r * 16 + lane] = a;
}

// ---------------------------------------------------------------------------
// jax.random.permutation reproduction: random bits + stable sort.
// random_bits (partitionable, 32-bit): counter i -> tf(k, hi=0, lo=i), o0^o1.
// ---------------------------------------------------------------------------
__global__ void k_genkeys(uint32_t ka, uint32_t kb, int n, uint32_t* __restrict__ keys)
{
  int i = blockIdx.x * blockDim.x + threadIdx.x;
  if (i < n) {
    uint32_t o0, o1;
    tf2x32(ka, kb, 0u, (uint32_t)i, o0, o1);
    keys[i] = o0 ^ o1;
  }
}

__global__ void k_iota(int* __restrict__ v, int n)
{
  int i = blockIdx.x * blockDim.x + threadIdx.x;
  if (i < n) v[i] = i;
}

__global__ void k_hist(const uint32_t* __restrict__ keys, int n, int* __restrict__ hist)
{
  int i = blockIdx.x * blockDim.x + threadIdx.x;
  if (i < n) atomicAdd(&hist[keys[i] >> 16], 1);
}

__global__ void k_sortscatter(const uint32_t* __restrict__ keys, const int* __restrict__ vals,
                              int n, int* __restrict__ cursor,
                              uint32_t* __restrict__ keyO, int* __restrict__ valO,
                              int* __restrict__ posO)
{
  int i = blockIdx.x * blockDim.x + threadIdx.x;
  if (i < n) {
    uint32_t k = keys[i];
    int p = atomicAdd(&cursor[k >> 16], 1);
    keyO[p] = k; valO[p] = vals[i]; posO[p] = i;
  }
}

// per-bucket insertion sort by (key, pos) -> exactly JAX's stable sort_key_val
__global__ void k_fixup(const int* __restrict__ offs, uint32_t* __restrict__ keyO,
                        int* __restrict__ valO, int* __restrict__ posO)
{
  int b = blockIdx.x * blockDim.x + threadIdx.x;
  if (b >= NBUCK) return;
  int s0 = offs[b], e0 = offs[b + 1];
  for (int i = s0 + 1; i < e0; ++i) {
    uint32_t k = keyO[i]; int v = valO[i], p = posO[i];
    int j = i - 1;
    while (j >= s0 && (keyO[j] > k || (keyO[j] == k && posO[j] > p))) {
      keyO[j + 1] = keyO[j]; valO[j + 1] = valO[j]; posO[j + 1] = posO[j];
      --j;
    }
    keyO[j + 1] = k; valO[j + 1] = v; posO[j + 1] = p;
  }
}

// ---------------------------------------------------------------------------
// host: one permutation = 2 rounds of stable sort by fresh random keys
// (num_rounds = ceil(3*ln(n)/ln(2^32-1)) = 2 for n in {100000, 200000})
// ---------------------------------------------------------------------------
static void run_sort(hipStream_t st, K2 kperm, int n, int* permOut,
                     uint32_t* keysA, int* valsA, uint32_t* keyB, int* valB,
                     int* posB, int* hist, int* offs)
{
  // key, subkey = split(key): keys[0]=tf(k,0,0)=next, keys[1]=tf(k,0,1)=subkey
  K2 knext = h_tf(kperm, 0u, 0u);
  K2 sub0  = h_tf(kperm, 0u, 1u);
  K2 sub1  = h_tf(knext, 0u, 1u);
  int nb = CEILDIV(n, 256);
  // round 0: payload = iota
  k_genkeys<<<nb, 256, 0, st>>>(sub0.a, sub0.b, n, keysA);
  k_iota<<<nb, 256, 0, st>>>(valsA, n);
  hipMemsetAsync(hist, 0, 4 * NBUCK, st);
  k_hist<<<nb, 256, 0, st>>>(keysA, n, hist);
  k_scan<<<1, 1024, 0, st>>>(hist, offs, hist, NBUCK);
  k_sortscatter<<<nb, 256, 0, st>>>(keysA, valsA, n, hist, keyB, valB, posB);
  k_fixup<<<CEILDIV(NBUCK, 256), 256, 0, st>>>(offs, keyB, valB, posB);
  // round 1: payload = round-0 result; output written directly into permOut
  k_genkeys<<<nb, 256, 0, st>>>(sub1.a, sub1.b, n, keysA);
  hipMemsetAsync(hist, 0, 4 * NBUCK, st);
  k_hist<<<nb, 256, 0, st>>>(keysA, n, hist);
  k_scan<<<1, 1024, 0, st>>>(hist, offs, hist, NBUCK);
  k_sortscatter<<<nb, 256, 0, st>>>(keysA, valB, n, hist, keyB, permOut, posB);
  k_fixup<<<CEILDIV(NBUCK, 256), 256, 0, st>>>(offs, keyB, permOut, posB);
}

// ---------------------------------------------------------------------------
extern "C" void kernel_launch(void* const* d_in, const int* in_sizes, int n_in,
                              void* d_out, int out_size, void* d_ws, size_t ws_size,
                              hipStream_t stream)
{
  const int*   u_id = (const int*)d_in[0];
  const int*   i_id = (const int*)d_in[1];
  const int*   T    = (const int*)d_in[2];
  const float* beta = (const float*)d_in[3];
  const float* UE   = (const float*)d_in[4];
  const float* IE   = (const float*)d_in[5];
  const float* W0   = (const float*)d_in[6];
  const float* W1   = (const float*)d_in[7];
  (void)in_sizes; (void)n_in; (void)out_size; (void)ws_size;

  float* out   = (float*)d_out;
  float* o_ufw = out;                                  // [NU,64]
  float* o_ifw = o_ufw + (size_t)NU * DD;              // [NI,64]
  float* o_up1 = o_ifw + (size_t)NI * DD;
  float* o_ip1 = o_up1 + (size_t)NU * DD;
  float* o_up2 = o_ip1 + (size_t)NI * DD;
  float* o_ip2 = o_up2 + (size_t)NU * DD;

  // --- workspace layout -----------------------------------------------------
  // persistent: CSR + perms.  phase-local (s | sort scratch | U/I ping-pong)
  // share one union region: the three phases are strictly sequential on
  // `stream`, so overlap is safe and shaves ~9 MB of footprint.
  char* wp = (char*)d_ws;
  auto carve = [&](size_t bytes) -> char* {
    char* r = wp; wp += (bytes + 255) & ~(size_t)255; return r;
  };
  int*      ptr_u = (int*)     carve(4ull * (NU + 1));
  int*      cnt_u = (int*)     carve(4ull * NU);
  int*      ptr_i = (int*)     carve(4ull * (NI + 1));
  int*      cnt_i = (int*)     carve(4ull * NI);
  int*      col_u = (int*)     carve(4ull * NE);
  float*    w_u   = (float*)   carve(4ull * NE);
  int*      col_i = (int*)     carve(4ull * NE);
  float*    w_i   = (float*)   carve(4ull * NE);
  int*      perms = (int*)     carve(4ull * 6 * (NU + NI));
  char*     uni   =            carve(4ull * 2 * (NU + NI) * DD);  // union region

  // phase C layout (propagation ping-pong)
  float* U1 = (float*)uni;
  float* U2 = U1 + (size_t)NU * DD;
  float* I1 = U2 + (size_t)NU * DD;
  float* I2 = I1 + (size_t)NI * DD;
  // phase A layout (edge weights)
  float* s = (float*)uni;
  // phase B layout (permutation sort scratch)
  uint32_t* keysA = (uint32_t*)uni;
  int*      valsA = (int*)(keysA + NU);
  uint32_t* keyB  = (uint32_t*)(valsA + NU);
  int*      valB  = (int*)(keyB + NU);
  int*      posB  = (int*)(valB + NU);
  int*      hist  = (int*)(posB + NU);
  int*      offs  = (int*)(hist + NBUCK);              // NBUCK+1 ints

  // 1. edge weights
  k_edge<<<CEILDIV(NE * 16, 256), 256, 0, stream>>>(u_id, i_id, T, beta, UE, IE, W0, W1, s);

  // 2. CSR in both directions (amortized over 9 SpMMs each)
  hipMemsetAsync(cnt_u, 0, 4 * NU, stream);
  hipMemsetAsync(cnt_i, 0, 4 * NI, stream);
  k_count<<<CEILDIV(NE, 256), 256, 0, stream>>>(u_id, i_id, cnt_u, cnt_i);
  k_scan<<<1, 1024, 0, stream>>>(cnt_u, ptr_u, cnt_u, NU);
  k_scan<<<1, 1024, 0, stream>>>(cnt_i, ptr_i, cnt_i, NI);
  k_scatter_csr<<<CEILDIV(NE, 256), 256, 0, stream>>>(u_id, i_id, s, cnt_u, cnt_i,
                                                      col_u, w_u, col_i, w_i);

  // 3. the 12 permutations (jax threefry, partitionable semantics)
  for (int p = 0; p < 2; ++p) {
    K2 base = {0u, (uint32_t)(p + 1)};                 // jax.random.key(p+1)
    for (int l = 0; l < 3; ++l) {
      K2 kl = h_tf(base, 0u, (uint32_t)l);             // fold_in(base, l)
      K2 ku = h_tf(kl, 0u, 0u);                        // split -> keys[0]
      K2 ki = h_tf(kl, 0u, 1u);                        // split -> keys[1]
      int* permU = perms + (size_t)(p * 3 + l) * (NU + NI);
      int* permI = permU + NU;
      run_sort(stream, ku, NU, permU, keysA, valsA, keyB, valB, posB, hist, offs);
      run_sort(stream, ki, NI, permI, keysA, valsA, keyB, valB, posB, hist, offs);
    }
  }

  const int GU = CEILDIV(NU * 16, 256), GI = CEILDIV(NI * 16, 256);
  const float THIRD = 1.0f / 3.0f;

  // 4. clean pass: u_{k+1}=A i_k ; i_{k+1}=A^T u_k ; mean over layers 1..3
  //    (layer-mean fused into the SpMM epilogue)
  k_spmm<<<GU, 256, 0, stream>>>(ptr_u, col_u, w_u, IE, U1, o_ufw, NU, 1, 1.0f);
  k_spmm<<<GI, 256, 0, stream>>>(ptr_i, col_i, w_i, UE, I1, o_ifw, NI, 1, 1.0f);
  k_spmm<<<GU, 256, 0, stream>>>(ptr_u, col_u, w_u, I1, U2, o_ufw, NU, 0, 1.0f);
  k_spmm<<<GI, 256, 0, stream>>>(ptr_i, col_i, w_i, U1, I2, o_ifw, NI, 0, 1.0f);
  k_spmm<<<GU, 256, 0, stream>>>(ptr_u, col_u, w_u, I2, U1, o_ufw, NU, 0, THIRD);
  k_spmm<<<GI, 256, 0, stream>>>(ptr_i, col_i, w_i, U2, I1, o_ifw, NI, 0, THIRD);

  // 5. two perturbed passes (noise + layer-mean fused in k_noise)
  for (int p = 0; p < 2; ++p) {
    float* accU = (p == 0) ? o_up1 : o_up2;
    float* accI = (p == 0) ? o_ip1 : o_ip2;
    const float* uP = UE;
    const float* iP = IE;
    for (int l = 0; l < 3; ++l) {
      int* permU = perms + (size_t)(p * 3 + l) * (NU + NI);
      int* permI = permU + NU;
      int first = (l == 0), isLast = (l == 2);
      float sc = isLast ? THIRD : 1.0f;
      k_spmm<<<GU, 256, 0, stream>>>(ptr_u, col_u, w_u, iP, U1, (float*)nullptr, NU, 0, 1.0f);
      k_spmm<<<GI, 256, 0, stream>>>(ptr_i, col_i, w_i, uP, I1, (float*)nullptr, NI, 0, 1.0f);
      k_noise<<<GU, 256, 0, stream>>>(U1, permU, U2, accU, NU, first, sc);
      k_noise<<<GI, 256, 0, stream>>>(I1, permI, I2, accI, NI, first, sc);
      uP = U2; iP = I2;
    }
  }
}

// Round 3
// 2301.084 us; speedup vs baseline: 2.9861x; 2.9861x over previous
//
#include <hip/hip_runtime.h>
#include <stdint.h>

#define NU 200000
#define NI 100000
#define DD 64
#define NE 1000000
#define EPSV 0.1f
#define NBUCK 65536
#define NSORT 12
#define PAIR (NU + NI)
#define TOTSORT (6 * PAIR)          // 1,800,000 elements across all 12 sorts
#define NBALL (NSORT * NBUCK)       // 786,432 buckets total
#define SCAN_TPB 256
#define SCAN_ELEMS 1024             // elements per scan block
#define CEILDIV(a,b) (((a)+(b)-1)/(b))

// ---------------------------------------------------------------------------
// Threefry-2x32 (20 rounds), matches jax._src.prng.threefry2x32 exactly.
// ---------------------------------------------------------------------------
__host__ __device__ inline void tf2x32(uint32_t k0, uint32_t k1,
                                       uint32_t x0, uint32_t x1,
                                       uint32_t &o0, uint32_t &o1) {
  uint32_t ks0 = k0, ks1 = k1, ks2 = k0 ^ k1 ^ 0x1BD11BDAu;
  x0 += ks0; x1 += ks1;
#define TF_RND(r) { x0 += x1; x1 = (x1 << (r)) | (x1 >> (32 - (r))); x1 ^= x0; }
  TF_RND(13) TF_RND(15) TF_RND(26) TF_RND(6)   x0 += ks1; x1 += ks2 + 1u;
  TF_RND(17) TF_RND(29) TF_RND(16) TF_RND(24)  x0 += ks2; x1 += ks0 + 2u;
  TF_RND(13) TF_RND(15) TF_RND(26) TF_RND(6)   x0 += ks0; x1 += ks1 + 3u;
  TF_RND(17) TF_RND(29) TF_RND(16) TF_RND(24)  x0 += ks1; x1 += ks2 + 4u;
  TF_RND(13) TF_RND(15) TF_RND(26) TF_RND(6)   x0 += ks2; x1 += ks0 + 5u;
#undef TF_RND
  o0 = x0; o1 = x1;
}

struct K2 { uint32_t a, b; };
static inline K2 h_tf(K2 k, uint32_t x0, uint32_t x1) {
  K2 r; tf2x32(k.a, k.b, x0, x1, r.a, r.b); return r;
}
// partitionable semantics: split -> key_j = tf(k, hi=0, lo=j); fold_in(d) = tf(k, 0, d).

struct SortKeys { uint32_t a[NSORT]; uint32_t b[NSORT]; };

// region r (0..11) of the concatenated sort array; local = index within region.
// Layout: 6 pairs of (U-region [NU], I-region [NI]).
__device__ inline void regionOf(int gid, int &r, int &local) {
  int pairIdx = gid / PAIR;
  int rem = gid - pairIdx * PAIR;
  if (rem < NU) { r = pairIdx * 2;     local = rem; }
  else          { r = pairIdx * 2 + 1; local = rem - NU; }
}

// ---------------------------------------------------------------------------
// Edge cosine weights. 16 lanes per edge, float4 per lane.
// ---------------------------------------------------------------------------
__global__ void k_edge(const int* __restrict__ u_id, const int* __restrict__ i_id,
                       const int* __restrict__ T, const float* __restrict__ betap,
                       const float* __restrict__ UE, const float* __restrict__ IE,
                       const float* __restrict__ W0, const float* __restrict__ W1,
                       float* __restrict__ s)
{
  int g = blockIdx.x * blockDim.x + threadIdx.x;
  int e = g >> 4, lane = g & 15;
  if (e >= NE) return;
  int u = u_id[e], it = i_id[e];
  float4 a = ((const float4*)UE)[u * 16 + lane];
  float4 b = ((const float4*)IE)[it * 16 + lane];
  float4 t;
  if (lane < 8) t = ((const float4*)W0)[T[2 * e] * 8 + lane];
  else          t = ((const float4*)W1)[T[2 * e + 1] * 8 + (lane - 8)];
  float ux = a.x + t.x, uy = a.y + t.y, uz = a.z + t.z, uw = a.w + t.w;
  float ix = b.x + t.x, iy = b.y + t.y, iz = b.z + t.z, iw = b.w + t.w;
  float uu = ux * ux + uy * uy + uz * uz + uw * uw;
  float ii = ix * ix + iy * iy + iz * iz + iw * iw;
  float ui = ux * ix + uy * iy + uz * iz + uw * iw;
#pragma unroll
  for (int m = 1; m < 16; m <<= 1) {
    uu += __shfl_xor(uu, m);
    ii += __shfl_xor(ii, m);
    ui += __shfl_xor(ui, m);
  }
  if (lane == 0) {
    float c = ui / (fmaxf(sqrtf(uu), 1e-12f) * fmaxf(sqrtf(ii), 1e-12f));
    float sv = (c + 1.0f) * 0.5f;
    s[e] = (sv < betap[0]) ? 0.0f : sv;
  }
}

// ---------------------------------------------------------------------------
// Hierarchical exclusive scan: scan1 (per-block sums) -> scan2 (scan of
// partials, single block, nb<=1024) -> scan3 (local rescan + offset).
// Writes offs[0..n-1], optional cursor copy, and endPtr=total (offs[n]).
// ---------------------------------------------------------------------------
__global__ void k_scan1(const int* __restrict__ in, int n, int* __restrict__ partials)
{
  __shared__ int sdata[SCAN_TPB];
  int base = blockIdx.x * SCAN_ELEMS;
  int sum = 0;
  for (int j = threadIdx.x; j < SCAN_ELEMS; j += SCAN_TPB) {
    int idx = base + j;
    if (idx < n) sum += in[idx];
  }
  sdata[threadIdx.x] = sum;
  __syncthreads();
  for (int off = SCAN_TPB / 2; off > 0; off >>= 1) {
    if (threadIdx.x < off) sdata[threadIdx.x] += sdata[threadIdx.x + off];
    __syncthreads();
  }
  if (threadIdx.x == 0) partials[blockIdx.x] = sdata[0];
}

__global__ void k_scan2(int* __restrict__ partials, int nb, int* __restrict__ endPtr)
{
  __shared__ int part[1024];
  int tid = threadIdx.x;
  part[tid] = (tid < nb) ? partials[tid] : 0;
  __syncthreads();
  for (int off = 1; off < 1024; off <<= 1) {
    int t = (tid >= off) ? part[tid - off] : 0;
    __syncthreads();
    part[tid] += t;
    __syncthreads();
  }
  if (tid < nb) partials[tid] = tid ? part[tid - 1] : 0;
  if (tid == 1023 && endPtr) *endPtr = part[1023];
}

__global__ void k_scan3(const int* __restrict__ in, int n,
                        const int* __restrict__ partials,
                        int* __restrict__ offs, int* __restrict__ cursor)
{
  __shared__ int sdata[SCAN_TPB];
  int base = blockIdx.x * SCAN_ELEMS + threadIdx.x * 4;
  int v[4];
#pragma unroll
  for (int q = 0; q < 4; ++q) v[q] = (base + q < n) ? in[base + q] : 0;
  int tsum = v[0] + v[1] + v[2] + v[3];
  sdata[threadIdx.x] = tsum;
  __syncthreads();
  for (int off = 1; off < SCAN_TPB; off <<= 1) {
    int t = (threadIdx.x >= off) ? sdata[threadIdx.x - off] : 0;
    __syncthreads();
    sdata[threadIdx.x] += t;
    __syncthreads();
  }
  int excl = partials[blockIdx.x] + (threadIdx.x ? sdata[threadIdx.x - 1] : 0);
#pragma unroll
  for (int q = 0; q < 4; ++q) {
    if (base + q < n) {
      offs[base + q] = excl;
      if (cursor) cursor[base + q] = excl;
      excl += v[q];
    }
  }
}

static void scan_ex(hipStream_t st, const int* in, int n, int* offs, int* cursor,
                    int* partials, int* endPtr)
{
  int nb = CEILDIV(n, SCAN_ELEMS);
  k_scan1<<<nb, SCAN_TPB, 0, st>>>(in, n, partials);
  k_scan2<<<1, 1024, 0, st>>>(partials, nb, endPtr);
  k_scan3<<<nb, SCAN_TPB, 0, st>>>(in, n, partials, offs, cursor);
}

// ---------------------------------------------------------------------------
// CSR build
// ---------------------------------------------------------------------------
__global__ void k_count(const int* __restrict__ u_id, const int* __restrict__ i_id,
                        int* __restrict__ cnt_u, int* __restrict__ cnt_i)
{
  int e = blockIdx.x * blockDim.x + threadIdx.x;
  if (e < NE) {
    atomicAdd(&cnt_u[u_id[e]], 1);
    atomicAdd(&cnt_i[i_id[e]], 1);
  }
}

__global__ void k_scatter_csr(const int* __restrict__ u_id, const int* __restrict__ i_id,
                              const float* __restrict__ s,
                              int* __restrict__ cur_u, int* __restrict__ cur_i,
                              int* __restrict__ col_u, float* __restrict__ w_u,
                              int* __restrict__ col_i, float* __restrict__ w_i)
{
  int e = blockIdx.x * blockDim.x + threadIdx.x;
  if (e < NE) {
    float w = s[e];
    int pu = atomicAdd(&cur_u[u_id[e]], 1);
    col_u[pu] = i_id[e]; w_u[pu] = w;
    int pi = atomicAdd(&cur_i[i_id[e]], 1);
    col_i[pi] = u_id[e]; w_i[pi] = w;
  }
}

// ---------------------------------------------------------------------------
// SpMM with fused layer-mean accumulation (16 lanes/row, float4/lane).
// ---------------------------------------------------------------------------
__global__ void k_spmm(const int* __restrict__ ptr, const int* __restrict__ col,
                       const float* __restrict__ w, const float* __restrict__ X,
                       float* __restrict__ Y, float* __restrict__ acc,
                       int nrows, int first, float scale)
{
  int g = blockIdx.x * blockDim.x + threadIdx.x;
  int r = g >> 4, lane = g & 15;
  if (r >= nrows) return;
  int b = ptr[r], e2 = ptr[r + 1];
  float4 a = make_float4(0.f, 0.f, 0.f, 0.f);
  for (int k = b; k < e2; ++k) {
    float wk = w[k];
    int c = col[k];
    float4 x = ((const float4*)X)[c * 16 + lane];
    a.x += wk * x.x; a.y += wk * x.y; a.z += wk * x.z; a.w += wk * x.w;
  }
  ((float4*)Y)[r * 16 + lane] = a;
  if (acc) {
    float4 v;
    if (first) v = a;
    else {
      v = ((const float4*)acc)[r * 16 + lane];
      v.x += a.x; v.y += a.y; v.z += a.z; v.w += a.w;
    }
    v.x *= scale; v.y *= scale; v.z *= scale; v.w *= scale;
    ((float4*)acc)[r * 16 + lane] = v;
  }
}

// O[r] = S[r] + EPS * l2norm(S[perm[r]]);  acc = (first ? O : acc+O) * scale
__global__ void k_noise(const float* __restrict__ S, const int* __restrict__ perm,
                        float* __restrict__ O, float* __restrict__ acc,
                        int nrows, int first, float scale)
{
  int g = blockIdx.x * blockDim.x + threadIdx.x;
  int r = g >> 4, lane = g & 15;
  if (r >= nrows) return;
  int pr = perm[r];
  float4 z = ((const float4*)S)[pr * 16 + lane];
  float ss = z.x * z.x + z.y * z.y + z.z * z.z + z.w * z.w;
#pragma unroll
  for (int m = 1; m < 16; m <<= 1) ss += __shfl_xor(ss, m);
  float coef = EPSV / fmaxf(sqrtf(ss), 1e-12f);
  float4 v = ((const float4*)S)[r * 16 + lane];
  v.x += coef * z.x; v.y += coef * z.y; v.z += coef * z.z; v.w += coef * z.w;
  ((float4*)O)[r * 16 + lane] = v;
  float4 a;
  if (first) a = v;
  else {
    a = ((const float4*)acc)[r * 16 + lane];
    a.x += v.x; a.y += v.y; a.z += v.z; a.w += v.w;
  }
  a.x *= scale; a.y *= scale; a.z *= scale; a.w *= scale;
  ((float4*)acc)[r * 16 + lane] = a;
}

// ---------------------------------------------------------------------------
// Batched permutation sort: all 12 sorts concatenated. One round =
// genkeys -> hist -> global scan (offsets double as region bases) ->
// scatter -> per-bucket stable fixup.
// random_bits (partitionable, 32-bit): counter i -> tf(k, hi=0, lo=i), o0^o1.
// ---------------------------------------------------------------------------
__global__ void k_genkeys_all(SortKeys sk, uint32_t* __restrict__ keys)
{
  int gid = blockIdx.x * blockDim.x + threadIdx.x;
  if (gid >= TOTSORT) return;
  int r, local; regionOf(gid, r, local);
  uint32_t o0, o1;
  tf2x32(sk.a[r], sk.b[r], 0u, (uint32_t)local, o0, o1);
  keys[gid] = o0 ^ o1;
}

__global__ void k_hist_all(const uint32_t* __restrict__ keys, int* __restrict__ hist)
{
  int gid = blockIdx.x * blockDim.x + threadIdx.x;
  if (gid >= TOTSORT) return;
  int r, local; regionOf(gid, r, local);
  atomicAdd(&hist[r * NBUCK + (keys[gid] >> 16)], 1);
}

// valsIn==nullptr -> payload is the local iota (round 0).
__global__ void k_scatter_all(const uint32_t* __restrict__ keys,
                              const int* __restrict__ valsIn,
                              int* __restrict__ cursor,
                              uint32_t* __restrict__ keyO, int* __restrict__ valO,
                              int* __restrict__ posO)
{
  int gid = blockIdx.x * blockDim.x + threadIdx.x;
  if (gid >= TOTSORT) return;
  int r, local; regionOf(gid, r, local);
  uint32_t k = keys[gid];
  int p = atomicAdd(&cursor[r * NBUCK + (k >> 16)], 1);
  keyO[p] = k;
  valO[p] = valsIn ? valsIn[gid] : local;
  posO[p] = local;
}

// per-bucket insertion sort by (key, pos) -> exactly JAX's stable sort_key_val
__global__ void k_fixup(const int* __restrict__ offs, uint32_t* __restrict__ keyO,
                        int* __restrict__ valO, int* __restrict__ posO)
{
  int b = blockIdx.x * blockDim.x + threadIdx.x;
  if (b >= NBALL) return;
  int s0 = offs[b], e0 = offs[b + 1];
  for (int i = s0 + 1; i < e0; ++i) {
    uint32_t k = keyO[i]; int v = valO[i], p = posO[i];
    int j = i - 1;
    while (j >= s0 && (keyO[j] > k || (keyO[j] == k && posO[j] > p))) {
      keyO[j + 1] = keyO[j]; valO[j + 1] = valO[j]; posO[j + 1] = posO[j];
      --j;
    }
    keyO[j + 1] = k; valO[j + 1] = v; posO[j + 1] = p;
  }
}

// ---------------------------------------------------------------------------
extern "C" void kernel_launch(void* const* d_in, const int* in_sizes, int n_in,
                              void* d_out, int out_size, void* d_ws, size_t ws_size,
                              hipStream_t stream)
{
  const int*   u_id = (const int*)d_in[0];
  const int*   i_id = (const int*)d_in[1];
  const int*   T    = (const int*)d_in[2];
  const float* beta = (const float*)d_in[3];
  const float* UE   = (const float*)d_in[4];
  const float* IE   = (const float*)d_in[5];
  const float* W0   = (const float*)d_in[6];
  const float* W1   = (const float*)d_in[7];
  (void)in_sizes; (void)n_in; (void)out_size; (void)ws_size;

  float* out   = (float*)d_out;
  float* o_ufw = out;                                  // [NU,64]
  float* o_ifw = o_ufw + (size_t)NU * DD;              // [NI,64]
  float* o_up1 = o_ifw + (size_t)NI * DD;
  float* o_ip1 = o_up1 + (size_t)NU * DD;
  float* o_up2 = o_ip1 + (size_t)NI * DD;
  float* o_ip2 = o_up2 + (size_t)NU * DD;

  // --- workspace ------------------------------------------------------------
  char* wp = (char*)d_ws;
  auto carve = [&](size_t bytes) -> char* {
    char* r = wp; wp += (bytes + 255) & ~(size_t)255; return r;
  };
  // persistent
  int*      ptr_u    = (int*)  carve(4ull * (NU + 1));
  int*      cnt_u    = (int*)  carve(4ull * NU);
  int*      cur_u    = (int*)  carve(4ull * NU);
  int*      ptr_i    = (int*)  carve(4ull * (NI + 1));
  int*      cnt_i    = (int*)  carve(4ull * NI);
  int*      cur_i    = (int*)  carve(4ull * NI);
  int*      col_u    = (int*)  carve(4ull * NE);
  float*    w_u      = (float*)carve(4ull * NE);
  int*      col_i    = (int*)  carve(4ull * NE);
  float*    w_i      = (float*)carve(4ull * NE);
  int*      perms    = (int*)  carve(4ull * TOTSORT);  // round-1 sorted payload
  int*      partials = (int*)  carve(4ull * 1025);
  // phase-local union region (edge s | sort scratch | propagation ping-pong)
  char*     uni      =         carve(4ull * 2 * (size_t)(NU + NI) * DD);

  // phase C (propagation)
  float* U1 = (float*)uni;
  float* U2 = U1 + (size_t)NU * DD;
  float* I1 = U2 + (size_t)NU * DD;
  float* I2 = I1 + (size_t)NI * DD;
  // phase A (edge weights)
  float* s = (float*)uni;
  // phase B (batched sort scratch) — ~38 MB, fits in the 153.6 MB union
  uint32_t* keysA = (uint32_t*)uni;              // TOTSORT
  uint32_t* keyB  = keysA + TOTSORT;             // TOTSORT
  int*      posB  = (int*)(keyB + TOTSORT);      // TOTSORT
  int*      val0  = posB + TOTSORT;              // TOTSORT (round-0 payload out)
  int*      hist  = val0 + TOTSORT;              // NBALL
  int*      offs  = hist + NBALL;                // NBALL+1
  int*      curs  = offs + NBALL + 1;            // NBALL

  // 1. edge weights
  k_edge<<<CEILDIV(NE * 16, 256), 256, 0, stream>>>(u_id, i_id, T, beta, UE, IE, W0, W1, s);

  // 2. CSR in both directions (amortized over 9 SpMMs each)
  hipMemsetAsync(cnt_u, 0, 4 * NU, stream);
  hipMemsetAsync(cnt_i, 0, 4 * NI, stream);
  k_count<<<CEILDIV(NE, 256), 256, 0, stream>>>(u_id, i_id, cnt_u, cnt_i);
  scan_ex(stream, cnt_u, NU, ptr_u, cur_u, partials, &ptr_u[NU]);
  scan_ex(stream, cnt_i, NI, ptr_i, cur_i, partials, &ptr_i[NI]);
  k_scatter_csr<<<CEILDIV(NE, 256), 256, 0, stream>>>(u_id, i_id, s, cur_u, cur_i,
                                                      col_u, w_u, col_i, w_i);

  // 3. all 12 permutations, batched into 2 stable-sort stages.
  //    perm = 2 rounds of stable sort by fresh threefry keys
  //    (num_rounds = ceil(3*ln(n)/ln(2^32)) = 2 for n in {1e5, 2e5}).
  SortKeys sk0, sk1;
  for (int p = 0; p < 2; ++p) {
    K2 base = {0u, (uint32_t)(p + 1)};                 // jax.random.key(p+1)
    for (int l = 0; l < 3; ++l) {
      K2 kl = h_tf(base, 0u, (uint32_t)l);             // fold_in(base, l)
      K2 kk[2] = { h_tf(kl, 0u, 0u), h_tf(kl, 0u, 1u) };  // split -> ku, ki
      for (int q = 0; q < 2; ++q) {
        int r = (p * 3 + l) * 2 + q;
        K2 kperm = kk[q];
        K2 knext = h_tf(kperm, 0u, 0u);                // split inside permutation
        K2 sub0  = h_tf(kperm, 0u, 1u);
        K2 sub1  = h_tf(knext, 0u, 1u);
        sk0.a[r] = sub0.a; sk0.b[r] = sub0.b;
        sk1.a[r] = sub1.a; sk1.b[r] = sub1.b;
      }
    }
  }
  const int GS = CEILDIV(TOTSORT, 256), GF = CEILDIV(NBALL, 256);
  // round 0: payload = iota -> val0
  k_genkeys_all<<<GS, 256, 0, stream>>>(sk0, keysA);
  hipMemsetAsync(hist, 0, 4ull * NBALL, stream);
  k_hist_all<<<GS, 256, 0, stream>>>(keysA, hist);
  scan_ex(stream, hist, NBALL, offs, curs, partials, &offs[NBALL]);
  k_scatter_all<<<GS, 256, 0, stream>>>(keysA, (const int*)nullptr, curs, keyB, val0, posB);
  k_fixup<<<GF, 256, 0, stream>>>(offs, keyB, val0, posB);
  // round 1: payload = round-0 result -> perms (the final permutations)
  k_genkeys_all<<<GS, 256, 0, stream>>>(sk1, keysA);
  hipMemsetAsync(hist, 0, 4ull * NBALL, stream);
  k_hist_all<<<GS, 256, 0, stream>>>(keysA, hist);
  scan_ex(stream, hist, NBALL, offs, curs, partials, &offs[NBALL]);
  k_scatter_all<<<GS, 256, 0, stream>>>(keysA, val0, curs, keyB, perms, posB);
  k_fixup<<<GF, 256, 0, stream>>>(offs, keyB, perms, posB);

  const int GU = CEILDIV(NU * 16, 256), GI = CEILDIV(NI * 16, 256);
  const float THIRD = 1.0f / 3.0f;

  // 4. clean pass (layer-mean fused into SpMM epilogue)
  k_spmm<<<GU, 256, 0, stream>>>(ptr_u, col_u, w_u, IE, U1, o_ufw, NU, 1, 1.0f);
  k_spmm<<<GI, 256, 0, stream>>>(ptr_i, col_i, w_i, UE, I1, o_ifw, NI, 1, 1.0f);
  k_spmm<<<GU, 256, 0, stream>>>(ptr_u, col_u, w_u, I1, U2, o_ufw, NU, 0, 1.0f);
  k_spmm<<<GI, 256, 0, stream>>>(ptr_i, col_i, w_i, U1, I2, o_ifw, NI, 0, 1.0f);
  k_spmm<<<GU, 256, 0, stream>>>(ptr_u, col_u, w_u, I2, U1, o_ufw, NU, 0, THIRD);
  k_spmm<<<GI, 256, 0, stream>>>(ptr_i, col_i, w_i, U2, I1, o_ifw, NI, 0, THIRD);

  // 5. two perturbed passes (noise + layer-mean fused in k_noise)
  for (int p = 0; p < 2; ++p) {
    float* accU = (p == 0) ? o_up1 : o_up2;
    float* accI = (p == 0) ? o_ip1 : o_ip2;
    const float* uP = UE;
    const float* iP = IE;
    for (int l = 0; l < 3; ++l) {
      int* permU = perms + (size_t)(p * 3 + l) * PAIR;
      int* permI = permU + NU;
      int first = (l == 0), isLast = (l == 2);
      float sc = isLast ? THIRD : 1.0f;
      k_spmm<<<GU, 256, 0, stream>>>(ptr_u, col_u, w_u, iP, U1, (float*)nullptr, NU, 0, 1.0f);
      k_spmm<<<GI, 256, 0, stream>>>(ptr_i, col_i, w_i, uP, I1, (float*)nullptr, NI, 0, 1.0f);
      k_noise<<<GU, 256, 0, stream>>>(U1, permU, U2, accU, NU, first, sc);
      k_noise<<<GI, 256, 0, stream>>>(I1, permI, I2, accI, NI, first, sc);
      uP = U2; iP = I2;
    }
  }
}

// Round 6
// 1956.912 us; speedup vs baseline: 3.5113x; 1.1759x over previous
//
#include <hip/hip_runtime.h>
#include <stdint.h>

#define NU 200000
#define NI 100000
#define DD 64
#define NE 1000000
#define EPSV 0.1f
#define NBUCK 65536
#define NSORT 12
#define PAIR (NU + NI)
#define TOTSORT (6 * PAIR)          // 1,800,000 elements across all 12 sorts
#define NBALL (NSORT * NBUCK)       // 786,432 buckets total
#define SCAN_TPB 256
#define SCAN_ELEMS 1024             // elements per scan block
#define CEILDIV(a,b) (((a)+(b)-1)/(b))

// ---------------------------------------------------------------------------
// Threefry-2x32 (20 rounds), matches jax._src.prng.threefry2x32 exactly.
// ---------------------------------------------------------------------------
__host__ __device__ inline void tf2x32(uint32_t k0, uint32_t k1,
                                       uint32_t x0, uint32_t x1,
                                       uint32_t &o0, uint32_t &o1) {
  uint32_t ks0 = k0, ks1 = k1, ks2 = k0 ^ k1 ^ 0x1BD11BDAu;
  x0 += ks0; x1 += ks1;
#define TF_RND(r) { x0 += x1; x1 = (x1 << (r)) | (x1 >> (32 - (r))); x1 ^= x0; }
  TF_RND(13) TF_RND(15) TF_RND(26) TF_RND(6)   x0 += ks1; x1 += ks2 + 1u;
  TF_RND(17) TF_RND(29) TF_RND(16) TF_RND(24)  x0 += ks2; x1 += ks0 + 2u;
  TF_RND(13) TF_RND(15) TF_RND(26) TF_RND(6)   x0 += ks0; x1 += ks1 + 3u;
  TF_RND(17) TF_RND(29) TF_RND(16) TF_RND(24)  x0 += ks1; x1 += ks2 + 4u;
  TF_RND(13) TF_RND(15) TF_RND(26) TF_RND(6)   x0 += ks2; x1 += ks0 + 5u;
#undef TF_RND
  o0 = x0; o1 = x1;
}

struct K2 { uint32_t a, b; };
static inline K2 h_tf(K2 k, uint32_t x0, uint32_t x1) {
  K2 r; tf2x32(k.a, k.b, x0, x1, r.a, r.b); return r;
}
// partitionable semantics: split -> key_j = tf(k, hi=0, lo=j); fold_in(d) = tf(k, 0, d).

struct SortKeys { uint32_t a[NSORT]; uint32_t b[NSORT]; };

// region r (0..11) of the concatenated sort array; local = index within region.
// Layout: 6 pairs of (U-region [NU], I-region [NI]).
__device__ inline void regionOf(int gid, int &r, int &local) {
  int pairIdx = gid / PAIR;
  int rem = gid - pairIdx * PAIR;
  if (rem < NU) { r = pairIdx * 2;     local = rem; }
  else          { r = pairIdx * 2 + 1; local = rem - NU; }
}

// ---------------------------------------------------------------------------
// Fused edge-weight + CSR scatter. 16 lanes/edge compute the cosine weight;
// lane 0 scatters packed (col, w) 8B records into both CSR directions.
// ---------------------------------------------------------------------------
__global__ void k_edgesc(const int* __restrict__ u_id, const int* __restrict__ i_id,
                         const int* __restrict__ T, const float* __restrict__ betap,
                         const float* __restrict__ UE, const float* __restrict__ IE,
                         const float* __restrict__ W0, const float* __restrict__ W1,
                         int* __restrict__ cur_u, int* __restrict__ cur_i,
                         uint2* __restrict__ colw_u, uint2* __restrict__ colw_i)
{
  int g = blockIdx.x * blockDim.x + threadIdx.x;
  int e = g >> 4, lane = g & 15;
  if (e >= NE) return;
  int u = u_id[e], it = i_id[e];
  float4 a = ((const float4*)UE)[u * 16 + lane];
  float4 b = ((const float4*)IE)[it * 16 + lane];
  float4 t;
  if (lane < 8) t = ((const float4*)W0)[T[2 * e] * 8 + lane];
  else          t = ((const float4*)W1)[T[2 * e + 1] * 8 + (lane - 8)];
  float ux = a.x + t.x, uy = a.y + t.y, uz = a.z + t.z, uw = a.w + t.w;
  float ix = b.x + t.x, iy = b.y + t.y, iz = b.z + t.z, iw = b.w + t.w;
  float uu = ux * ux + uy * uy + uz * uz + uw * uw;
  float ii = ix * ix + iy * iy + iz * iz + iw * iw;
  float ui = ux * ix + uy * iy + uz * iz + uw * iw;
#pragma unroll
  for (int m = 1; m < 16; m <<= 1) {
    uu += __shfl_xor(uu, m);
    ii += __shfl_xor(ii, m);
    ui += __shfl_xor(ui, m);
  }
  if (lane == 0) {
    float c = ui / (fmaxf(sqrtf(uu), 1e-12f) * fmaxf(sqrtf(ii), 1e-12f));
    float sv = (c + 1.0f) * 0.5f;
    float w = (sv < betap[0]) ? 0.0f : sv;
    uint32_t wb = __float_as_uint(w);
    int pu = atomicAdd(&cur_u[u], 1);
    colw_u[pu] = make_uint2((uint32_t)it, wb);
    int pi = atomicAdd(&cur_i[it], 1);
    colw_i[pi] = make_uint2((uint32_t)u, wb);
  }
}

// ---------------------------------------------------------------------------
// Hierarchical exclusive scan: scan1 -> scan2 (single block) -> scan3.
// ---------------------------------------------------------------------------
__global__ void k_scan1(const int* __restrict__ in, int n, int* __restrict__ partials)
{
  __shared__ int sdata[SCAN_TPB];
  int base = blockIdx.x * SCAN_ELEMS;
  int sum = 0;
  for (int j = threadIdx.x; j < SCAN_ELEMS; j += SCAN_TPB) {
    int idx = base + j;
    if (idx < n) sum += in[idx];
  }
  sdata[threadIdx.x] = sum;
  __syncthreads();
  for (int off = SCAN_TPB / 2; off > 0; off >>= 1) {
    if (threadIdx.x < off) sdata[threadIdx.x] += sdata[threadIdx.x + off];
    __syncthreads();
  }
  if (threadIdx.x == 0) partials[blockIdx.x] = sdata[0];
}

__global__ void k_scan2(int* __restrict__ partials, int nb, int* __restrict__ endPtr)
{
  __shared__ int part[1024];
  int tid = threadIdx.x;
  part[tid] = (tid < nb) ? partials[tid] : 0;
  __syncthreads();
  for (int off = 1; off < 1024; off <<= 1) {
    int t = (tid >= off) ? part[tid - off] : 0;
    __syncthreads();
    part[tid] += t;
    __syncthreads();
  }
  if (tid < nb) partials[tid] = tid ? part[tid - 1] : 0;
  if (tid == 1023 && endPtr) *endPtr = part[1023];
}

__global__ void k_scan3(const int* __restrict__ in, int n,
                        const int* __restrict__ partials,
                        int* __restrict__ offs, int* __restrict__ cursor)
{
  __shared__ int sdata[SCAN_TPB];
  int base = blockIdx.x * SCAN_ELEMS + threadIdx.x * 4;
  int v[4];
#pragma unroll
  for (int q = 0; q < 4; ++q) v[q] = (base + q < n) ? in[base + q] : 0;
  int tsum = v[0] + v[1] + v[2] + v[3];
  sdata[threadIdx.x] = tsum;
  __syncthreads();
  for (int off = 1; off < SCAN_TPB; off <<= 1) {
    int t = (threadIdx.x >= off) ? sdata[threadIdx.x - off] : 0;
    __syncthreads();
    sdata[threadIdx.x] += t;
    __syncthreads();
  }
  int excl = partials[blockIdx.x] + (threadIdx.x ? sdata[threadIdx.x - 1] : 0);
#pragma unroll
  for (int q = 0; q < 4; ++q) {
    if (base + q < n) {
      offs[base + q] = excl;
      if (cursor) cursor[base + q] = excl;
      excl += v[q];
    }
  }
}

static void scan_ex(hipStream_t st, const int* in, int n, int* offs, int* cursor,
                    int* partials, int* endPtr)
{
  int nb = CEILDIV(n, SCAN_ELEMS);
  k_scan1<<<nb, SCAN_TPB, 0, st>>>(in, n, partials);
  k_scan2<<<1, 1024, 0, st>>>(partials, nb, endPtr);
  k_scan3<<<nb, SCAN_TPB, 0, st>>>(in, n, partials, offs, cursor);
}

__global__ void k_count(const int* __restrict__ u_id, const int* __restrict__ i_id,
                        int* __restrict__ cnt_u, int* __restrict__ cnt_i)
{
  int e = blockIdx.x * blockDim.x + threadIdx.x;
  if (e < NE) {
    atomicAdd(&cnt_u[u_id[e]], 1);
    atomicAdd(&cnt_i[i_id[e]], 1);
  }
}

// ---------------------------------------------------------------------------
// Combined two-sided SpMM over PAIR rows (u rows [0,NU), i rows [NU,PAIR)).
//   side u: Y[r] = A  · Xi_in   (cols are item ids, gather Xi_in)
//   side i: Y[r] = Aᵀ · Xu_in   (cols are user ids, gather Xu_in)
// Y / acc are PAIR-contiguous. 16 lanes/row, float4/lane. The u/i boundary
// (NU*16/256 = 12500) falls exactly on a block boundary -> no divergence.
// ---------------------------------------------------------------------------
__global__ void k_spmm2(const int* __restrict__ ptr_u, const uint2* __restrict__ colw_u,
                        const float* __restrict__ Xi_in,
                        const int* __restrict__ ptr_i, const uint2* __restrict__ colw_i,
                        const float* __restrict__ Xu_in,
                        float* __restrict__ Y, float* __restrict__ acc,
                        int first, float scale, int writeY)
{
  int g = blockIdx.x * blockDim.x + threadIdx.x;
  int r = g >> 4, lane = g & 15;
  if (r >= PAIR) return;
  const int* ptr; const uint2* colw; const float4* X; int rr;
  if (r < NU) { ptr = ptr_u; colw = colw_u; X = (const float4*)Xi_in; rr = r; }
  else        { ptr = ptr_i; colw = colw_i; X = (const float4*)Xu_in; rr = r - NU; }
  int b = ptr[rr], e2 = ptr[rr + 1];
  float4 a = make_float4(0.f, 0.f, 0.f, 0.f);
  for (int k = b; k < e2; ++k) {
    uint2 cw = colw[k];
    float wk = __uint_as_float(cw.y);
    float4 x = X[(size_t)cw.x * 16 + lane];
    a.x += wk * x.x; a.y += wk * x.y; a.z += wk * x.z; a.w += wk * x.w;
  }
  if (writeY) ((float4*)Y)[r * 16 + lane] = a;
  if (acc) {
    float4 v;
    if (first) v = a;
    else {
      v = ((const float4*)acc)[r * 16 + lane];
      v.x += a.x; v.y += a.y; v.z += a.z; v.w += a.w;
    }
    v.x *= scale; v.y *= scale; v.z *= scale; v.w *= scale;
    ((float4*)acc)[r * 16 + lane] = v;
  }
}

// ---------------------------------------------------------------------------
// Combined two-sided noise + layer-mean:
//   O[r] = S[r] + EPS * l2norm(S[perm-row]);  acc = (first ? O : acc+O)*scale
// perm is the [U;I]-contiguous permutation block; values are region-local.
// ---------------------------------------------------------------------------
__global__ void k_noise2(const float* __restrict__ S, const int* __restrict__ perm,
                         float* __restrict__ O, float* __restrict__ acc,
                         int first, float scale, int writeO)
{
  int g = blockIdx.x * blockDim.x + threadIdx.x;
  int r = g >> 4, lane = g & 15;
  if (r >= PAIR) return;
  int pr = (r < NU) ? perm[r] : NU + perm[r];
  float4 z = ((const float4*)S)[(size_t)pr * 16 + lane];
  float ss = z.x * z.x + z.y * z.y + z.z * z.z + z.w * z.w;
#pragma unroll
  for (int m = 1; m < 16; m <<= 1) ss += __shfl_xor(ss, m);
  float coef = EPSV / fmaxf(sqrtf(ss), 1e-12f);
  float4 v = ((const float4*)S)[(size_t)r * 16 + lane];
  v.x += coef * z.x; v.y += coef * z.y; v.z += coef * z.z; v.w += coef * z.w;
  if (writeO) ((float4*)O)[r * 16 + lane] = v;
  float4 a;
  if (first) a = v;
  else {
    a = ((const float4*)acc)[r * 16 + lane];
    a.x += v.x; a.y += v.y; a.z += v.z; a.w += v.w;
  }
  a.x *= scale; a.y *= scale; a.z *= scale; a.w *= scale;
  ((float4*)acc)[r * 16 + lane] = a;
}

// ---------------------------------------------------------------------------
// Batched permutation sort (12 sorts, 2 stable-sort rounds).
// ---------------------------------------------------------------------------
__global__ void k_genkeys_all(SortKeys sk, uint32_t* __restrict__ keys)
{
  int gid = blockIdx.x * blockDim.x + threadIdx.x;
  if (gid >= TOTSORT) return;
  int r, local; regionOf(gid, r, local);
  uint32_t o0, o1;
  tf2x32(sk.a[r], sk.b[r], 0u, (uint32_t)local, o0, o1);
  keys[gid] = o0 ^ o1;
}

__global__ void k_hist_all(const uint32_t* __restrict__ keys, int* __restrict__ hist)
{
  int gid = blockIdx.x * blockDim.x + threadIdx.x;
  if (gid >= TOTSORT) return;
  int r, local; regionOf(gid, r, local);
  atomicAdd(&hist[r * NBUCK + (keys[gid] >> 16)], 1);
}

__global__ void k_scatter_all(const uint32_t* __restrict__ keys,
                              const int* __restrict__ valsIn,
                              int* __restrict__ cursor,
                              uint32_t* __restrict__ keyO, int* __restrict__ valO,
                              int* __restrict__ posO)
{
  int gid = blockIdx.x * blockDim.x + threadIdx.x;
  if (gid >= TOTSORT) return;
  int r, local; regionOf(gid, r, local);
  uint32_t k = keys[gid];
  int p = atomicAdd(&cursor[r * NBUCK + (k >> 16)], 1);
  keyO[p] = k;
  valO[p] = valsIn ? valsIn[gid] : local;
  posO[p] = local;
}

__global__ void k_fixup(const int* __restrict__ offs, uint32_t* __restrict__ keyO,
                        int* __restrict__ valO, int* __restrict__ posO)
{
  int b = blockIdx.x * blockDim.x + threadIdx.x;
  if (b >= NBALL) return;
  int s0 = offs[b], e0 = offs[b + 1];
  for (int i = s0 + 1; i < e0; ++i) {
    uint32_t k = keyO[i]; int v = valO[i], p = posO[i];
    int j = i - 1;
    while (j >= s0 && (keyO[j] > k || (keyO[j] == k && posO[j] > p))) {
      keyO[j + 1] = keyO[j]; valO[j + 1] = valO[j]; posO[j + 1] = posO[j];
      --j;
    }
    keyO[j + 1] = k; valO[j + 1] = v; posO[j + 1] = p;
  }
}

// ---------------------------------------------------------------------------
extern "C" void kernel_launch(void* const* d_in, const int* in_sizes, int n_in,
                              void* d_out, int out_size, void* d_ws, size_t ws_size,
                              hipStream_t stream)
{
  const int*   u_id = (const int*)d_in[0];
  const int*   i_id = (const int*)d_in[1];
  const int*   T    = (const int*)d_in[2];
  const float* beta = (const float*)d_in[3];
  const float* UE   = (const float*)d_in[4];
  const float* IE   = (const float*)d_in[5];
  const float* W0   = (const float*)d_in[6];
  const float* W1   = (const float*)d_in[7];
  (void)in_sizes; (void)n_in; (void)out_size;

  float* out    = (float*)d_out;
  float* accCln = out;                                 // [PAIR,64] (ufw;ifw)
  float* accP0  = out + (size_t)PAIR * DD;             // [PAIR,64] (up1;ip1)
  float* accP1  = out + 2ull * PAIR * DD;              // [PAIR,64] (up2;ip2)

  // --- workspace ------------------------------------------------------------
  char* wp = (char*)d_ws;
  auto carve = [&](size_t bytes) -> char* {
    char* r = wp; wp += (bytes + 255) & ~(size_t)255; return r;
  };
  int*   ptr_u    = (int*)  carve(4ull * (NU + 1));
  int*   cnt_u    = (int*)  carve(4ull * NU);
  int*   cur_u    = (int*)  carve(4ull * NU);
  int*   ptr_i    = (int*)  carve(4ull * (NI + 1));
  int*   cnt_i    = (int*)  carve(4ull * NI);
  int*   cur_i    = (int*)  carve(4ull * NI);
  uint2* colw_u   = (uint2*)carve(8ull * NE);
  uint2* colw_i   = (uint2*)carve(8ull * NE);
  int*   perms    = (int*)  carve(4ull * TOTSORT);
  int*   partials = (int*)  carve(4ull * 1025);

  const size_t PB = (size_t)PAIR * DD * 4;             // 76.8 MB per pair buffer
  size_t used = (size_t)(wp - (char*)d_ws);
  // share layer-1 raw SpMM across the 3 passes if a third pair buffer fits.
  // ws_size is constant for the session -> identical work every call.
  bool share = ws_size >= used + 3 * PB;
  char* uni = carve(share ? 3 * PB : 2 * PB);

  float* P0 = (float*)uni;            // pair buffer 0 [PAIR,64]
  float* P1 = P0 + (size_t)PAIR * DD; // pair buffer 1
  float* P2 = share ? P1 + (size_t)PAIR * DD : nullptr;

  // sort scratch overlays the pair buffers (phases strictly sequential)
  uint32_t* keysA = (uint32_t*)uni;              // TOTSORT
  uint32_t* keyB  = keysA + TOTSORT;             // TOTSORT
  int*      posB  = (int*)(keyB + TOTSORT);      // TOTSORT
  int*      val0  = posB + TOTSORT;              // TOTSORT
  int*      hist  = val0 + TOTSORT;              // NBALL
  int*      offs  = hist + NBALL;                // NBALL+1
  int*      curs  = offs + NBALL + 1;            // NBALL

  // 1. CSR counts + offsets, then fused edge-weight + packed scatter
  hipMemsetAsync(cnt_u, 0, 4 * NU, stream);
  hipMemsetAsync(cnt_i, 0, 4 * NI, stream);
  k_count<<<CEILDIV(NE, 256), 256, 0, stream>>>(u_id, i_id, cnt_u, cnt_i);
  scan_ex(stream, cnt_u, NU, ptr_u, cur_u, partials, &ptr_u[NU]);
  scan_ex(stream, cnt_i, NI, ptr_i, cur_i, partials, &ptr_i[NI]);
  k_edgesc<<<CEILDIV(NE * 16, 256), 256, 0, stream>>>(u_id, i_id, T, beta, UE, IE,
                                                      W0, W1, cur_u, cur_i,
                                                      colw_u, colw_i);

  // 2. all 12 permutations, batched into 2 stable-sort stages
  SortKeys sk0, sk1;
  for (int p = 0; p < 2; ++p) {
    K2 base = {0u, (uint32_t)(p + 1)};                 // jax.random.key(p+1)
    for (int l = 0; l < 3; ++l) {
      K2 kl = h_tf(base, 0u, (uint32_t)l);             // fold_in(base, l)
      K2 kk[2] = { h_tf(kl, 0u, 0u), h_tf(kl, 0u, 1u) };  // split -> ku, ki
      for (int q = 0; q < 2; ++q) {
        int r = (p * 3 + l) * 2 + q;
        K2 kperm = kk[q];
        K2 knext = h_tf(kperm, 0u, 0u);                // split inside permutation
        K2 sub0  = h_tf(kperm, 0u, 1u);
        K2 sub1  = h_tf(knext, 0u, 1u);
        sk0.a[r] = sub0.a; sk0.b[r] = sub0.b;
        sk1.a[r] = sub1.a; sk1.b[r] = sub1.b;
      }
    }
  }
  const int GS = CEILDIV(TOTSORT, 256), GF = CEILDIV(NBALL, 256);
  k_genkeys_all<<<GS, 256, 0, stream>>>(sk0, keysA);
  hipMemsetAsync(hist, 0, 4ull * NBALL, stream);
  k_hist_all<<<GS, 256, 0, stream>>>(keysA, hist);
  scan_ex(stream, hist, NBALL, offs, curs, partials, &offs[NBALL]);
  k_scatter_all<<<GS, 256, 0, stream>>>(keysA, (const int*)nullptr, curs, keyB, val0, posB);
  k_fixup<<<GF, 256, 0, stream>>>(offs, keyB, val0, posB);
  k_genkeys_all<<<GS, 256, 0, stream>>>(sk1, keysA);
  hipMemsetAsync(hist, 0, 4ull * NBALL, stream);
  k_hist_all<<<GS, 256, 0, stream>>>(keysA, hist);
  scan_ex(stream, hist, NBALL, offs, curs, partials, &offs[NBALL]);
  k_scatter_all<<<GS, 256, 0, stream>>>(keysA, val0, curs, keyB, perms, posB);
  k_fixup<<<GF, 256, 0, stream>>>(offs, keyB, perms, posB);

  // 3. propagation
  const int GP = CEILDIV(PAIR * 16, 256);
  const float THIRD = 1.0f / 3.0f;
  auto SPMM = [&](const float* Xi_in, const float* Xu_in, float* Y, float* acc,
                  int first, float scale, int writeY) {
    k_spmm2<<<GP, 256, 0, stream>>>(ptr_u, colw_u, Xi_in, ptr_i, colw_i, Xu_in,
                                    Y, acc, first, scale, writeY);
  };
  auto NOISE = [&](const float* S, int pass, int layer, float* O, float* acc,
                   int first, float scale, int writeO) {
    k_noise2<<<GP, 256, 0, stream>>>(S, perms + (size_t)(pass * 3 + layer) * PAIR,
                                     O, acc, first, scale, writeO);
  };

  if (share) {
    // raw layer-1 (shared by all 3 passes) -> P0; clean acc init
    SPMM(IE, UE, P0, accCln, 1, 1.0f, 1);
    // clean layers 2,3 (clean uses raw chain)
    SPMM(P0 + (size_t)NU * DD, P0, P1, accCln, 0, 1.0f, 1);
    SPMM(P1 + (size_t)NU * DD, P1, nullptr, accCln, 0, THIRD, 0);
    for (int p = 0; p < 2; ++p) {
      float* acc = p ? accP1 : accP0;
      NOISE(P0, p, 0, P1, acc, 1, 1.0f, 1);                      // layer 1
      SPMM(P1 + (size_t)NU * DD, P1, P2, nullptr, 0, 1.0f, 1);   // layer 2
      NOISE(P2, p, 1, P1, acc, 0, 1.0f, 1);
      SPMM(P1 + (size_t)NU * DD, P1, P2, nullptr, 0, 1.0f, 1);   // layer 3
      NOISE(P2, p, 2, nullptr, acc, 0, THIRD, 0);
    }
  } else {
    // clean pass
    SPMM(IE, UE, P0, accCln, 1, 1.0f, 1);
    SPMM(P0 + (size_t)NU * DD, P0, P1, accCln, 0, 1.0f, 1);
    SPMM(P1 + (size_t)NU * DD, P1, nullptr, accCln, 0, THIRD, 0);
    // perturbed passes (recompute layer 1)
    for (int p = 0; p < 2; ++p) {
      float* acc = p ? accP1 : accP0;
      SPMM(IE, UE, P0, nullptr, 0, 1.0f, 1);
      NOISE(P0, p, 0, P1, acc, 1, 1.0f, 1);
      SPMM(P1 + (size_t)NU * DD, P1, P0, nullptr, 0, 1.0f, 1);
      NOISE(P0, p, 1, P1, acc, 0, 1.0f, 1);
      SPMM(P1 + (size_t)NU * DD, P1, P0, nullptr, 0, 1.0f, 1);
      NOISE(P0, p, 2, nullptr, acc, 0, THIRD, 0);
    }
  }
}

// Round 7
// 1874.005 us; speedup vs baseline: 3.6666x; 1.0442x over previous
//
#include <hip/hip_runtime.h>
#include <stdint.h>

#define NU 200000
#define NI 100000
#define DD 64
#define NE 1000000
#define EPSV 0.1f
#define NBUCK 65536
#define NSORT 12
#define PAIR (NU + NI)
#define TOTSORT (6 * PAIR)          // 1,800,000 elements across all 12 sorts
#define NBALL (NSORT * NBUCK)       // 786,432 buckets total
#define SCAN_TPB 256
#define SCAN_ELEMS 1024             // elements per scan block
#define CEILDIV(a,b) (((a)+(b)-1)/(b))

// ---------------------------------------------------------------------------
// Threefry-2x32 (20 rounds), matches jax._src.prng.threefry2x32 exactly.
// ---------------------------------------------------------------------------
__host__ __device__ inline void tf2x32(uint32_t k0, uint32_t k1,
                                       uint32_t x0, uint32_t x1,
                                       uint32_t &o0, uint32_t &o1) {
  uint32_t ks0 = k0, ks1 = k1, ks2 = k0 ^ k1 ^ 0x1BD11BDAu;
  x0 += ks0; x1 += ks1;
#define TF_RND(r) { x0 += x1; x1 = (x1 << (r)) | (x1 >> (32 - (r))); x1 ^= x0; }
  TF_RND(13) TF_RND(15) TF_RND(26) TF_RND(6)   x0 += ks1; x1 += ks2 + 1u;
  TF_RND(17) TF_RND(29) TF_RND(16) TF_RND(24)  x0 += ks2; x1 += ks0 + 2u;
  TF_RND(13) TF_RND(15) TF_RND(26) TF_RND(6)   x0 += ks0; x1 += ks1 + 3u;
  TF_RND(17) TF_RND(29) TF_RND(16) TF_RND(24)  x0 += ks1; x1 += ks2 + 4u;
  TF_RND(13) TF_RND(15) TF_RND(26) TF_RND(6)   x0 += ks2; x1 += ks0 + 5u;
#undef TF_RND
  o0 = x0; o1 = x1;
}

struct K2 { uint32_t a, b; };
static inline K2 h_tf(K2 k, uint32_t x0, uint32_t x1) {
  K2 r; tf2x32(k.a, k.b, x0, x1, r.a, r.b); return r;
}
// partitionable semantics: split -> key_j = tf(k, hi=0, lo=j); fold_in(d) = tf(k, 0, d).

struct SortKeys { uint32_t a[NSORT]; uint32_t b[NSORT]; };

// region r (0..11) of the concatenated sort array; local = index within region.
// Layout: 6 pairs of (U-region [NU], I-region [NI]).
__device__ inline void regionOf(int gid, int &r, int &local) {
  int pairIdx = gid / PAIR;
  int rem = gid - pairIdx * PAIR;
  if (rem < NU) { r = pairIdx * 2;     local = rem; }
  else          { r = pairIdx * 2 + 1; local = rem - NU; }
}

// ---------------------------------------------------------------------------
// Fused edge-weight + CSR scatter. 16 lanes/edge compute the cosine weight;
// lane 0 scatters packed (col, w) 8B records into both CSR directions.
// ---------------------------------------------------------------------------
__global__ void k_edgesc(const int* __restrict__ u_id, const int* __restrict__ i_id,
                         const int* __restrict__ T, const float* __restrict__ betap,
                         const float* __restrict__ UE, const float* __restrict__ IE,
                         const float* __restrict__ W0, const float* __restrict__ W1,
                         int* __restrict__ cur_u, int* __restrict__ cur_i,
                         uint2* __restrict__ colw_u, uint2* __restrict__ colw_i)
{
  int g = blockIdx.x * blockDim.x + threadIdx.x;
  int e = g >> 4, lane = g & 15;
  if (e >= NE) return;
  int u = u_id[e], it = i_id[e];
  float4 a = ((const float4*)UE)[u * 16 + lane];
  float4 b = ((const float4*)IE)[it * 16 + lane];
  float4 t;
  if (lane < 8) t = ((const float4*)W0)[T[2 * e] * 8 + lane];
  else          t = ((const float4*)W1)[T[2 * e + 1] * 8 + (lane - 8)];
  float ux = a.x + t.x, uy = a.y + t.y, uz = a.z + t.z, uw = a.w + t.w;
  float ix = b.x + t.x, iy = b.y + t.y, iz = b.z + t.z, iw = b.w + t.w;
  float uu = ux * ux + uy * uy + uz * uz + uw * uw;
  float ii = ix * ix + iy * iy + iz * iz + iw * iw;
  float ui = ux * ix + uy * iy + uz * iz + uw * iw;
#pragma unroll
  for (int m = 1; m < 16; m <<= 1) {
    uu += __shfl_xor(uu, m);
    ii += __shfl_xor(ii, m);
    ui += __shfl_xor(ui, m);
  }
  if (lane == 0) {
    float c = ui / (fmaxf(sqrtf(uu), 1e-12f) * fmaxf(sqrtf(ii), 1e-12f));
    float sv = (c + 1.0f) * 0.5f;
    float w = (sv < betap[0]) ? 0.0f : sv;
    uint32_t wb = __float_as_uint(w);
    int pu = atomicAdd(&cur_u[u], 1);
    colw_u[pu] = make_uint2((uint32_t)it, wb);
    int pi = atomicAdd(&cur_i[it], 1);
    colw_i[pi] = make_uint2((uint32_t)u, wb);
  }
}

// ---------------------------------------------------------------------------
// Hierarchical exclusive scan: scan1 -> scan2 (single block) -> scan3.
// ---------------------------------------------------------------------------
__global__ void k_scan1(const int* __restrict__ in, int n, int* __restrict__ partials)
{
  __shared__ int sdata[SCAN_TPB];
  int base = blockIdx.x * SCAN_ELEMS;
  int sum = 0;
  for (int j = threadIdx.x; j < SCAN_ELEMS; j += SCAN_TPB) {
    int idx = base + j;
    if (idx < n) sum += in[idx];
  }
  sdata[threadIdx.x] = sum;
  __syncthreads();
  for (int off = SCAN_TPB / 2; off > 0; off >>= 1) {
    if (threadIdx.x < off) sdata[threadIdx.x] += sdata[threadIdx.x + off];
    __syncthreads();
  }
  if (threadIdx.x == 0) partials[blockIdx.x] = sdata[0];
}

__global__ void k_scan2(int* __restrict__ partials, int nb, int* __restrict__ endPtr)
{
  __shared__ int part[1024];
  int tid = threadIdx.x;
  part[tid] = (tid < nb) ? partials[tid] : 0;
  __syncthreads();
  for (int off = 1; off < 1024; off <<= 1) {
    int t = (tid >= off) ? part[tid - off] : 0;
    __syncthreads();
    part[tid] += t;
    __syncthreads();
  }
  if (tid < nb) partials[tid] = tid ? part[tid - 1] : 0;
  if (tid == 1023 && endPtr) *endPtr = part[1023];
}

__global__ void k_scan3(const int* __restrict__ in, int n,
                        const int* __restrict__ partials,
                        int* __restrict__ offs, int* __restrict__ cursor)
{
  __shared__ int sdata[SCAN_TPB];
  int base = blockIdx.x * SCAN_ELEMS + threadIdx.x * 4;
  int v[4];
#pragma unroll
  for (int q = 0; q < 4; ++q) v[q] = (base + q < n) ? in[base + q] : 0;
  int tsum = v[0] + v[1] + v[2] + v[3];
  sdata[threadIdx.x] = tsum;
  __syncthreads();
  for (int off = 1; off < SCAN_TPB; off <<= 1) {
    int t = (threadIdx.x >= off) ? sdata[threadIdx.x - off] : 0;
    __syncthreads();
    sdata[threadIdx.x] += t;
    __syncthreads();
  }
  int excl = partials[blockIdx.x] + (threadIdx.x ? sdata[threadIdx.x - 1] : 0);
#pragma unroll
  for (int q = 0; q < 4; ++q) {
    if (base + q < n) {
      offs[base + q] = excl;
      if (cursor) cursor[base + q] = excl;
      excl += v[q];
    }
  }
}

static void scan_ex(hipStream_t st, const int* in, int n, int* offs, int* cursor,
                    int* partials, int* endPtr)
{
  int nb = CEILDIV(n, SCAN_ELEMS);
  k_scan1<<<nb, SCAN_TPB, 0, st>>>(in, n, partials);
  k_scan2<<<1, 1024, 0, st>>>(partials, nb, endPtr);
  k_scan3<<<nb, SCAN_TPB, 0, st>>>(in, n, partials, offs, cursor);
}

__global__ void k_count(const int* __restrict__ u_id, const int* __restrict__ i_id,
                        int* __restrict__ cnt_u, int* __restrict__ cnt_i)
{
  int e = blockIdx.x * blockDim.x + threadIdx.x;
  if (e < NE) {
    atomicAdd(&cnt_u[u_id[e]], 1);
    atomicAdd(&cnt_i[i_id[e]], 1);
  }
}

// ---------------------------------------------------------------------------
// Combined two-sided SpMM over PAIR rows (u rows [0,NU), i rows [NU,PAIR)).
//   side u: Y[r] = A  · Xi_in   (cols are item ids, gather Xi_in)
//   side i: Y[r] = Aᵀ · Xu_in   (cols are user ids, gather Xu_in)
// 16 lanes/row, float4/lane; 2x unrolled k-loop for gather MLP.
// u/i boundary (NU*16/256 = 12500) falls exactly on a block boundary.
// ---------------------------------------------------------------------------
__global__ void k_spmm2(const int* __restrict__ ptr_u, const uint2* __restrict__ colw_u,
                        const float* __restrict__ Xi_in,
                        const int* __restrict__ ptr_i, const uint2* __restrict__ colw_i,
                        const float* __restrict__ Xu_in,
                        float* __restrict__ Y, float* __restrict__ acc,
                        int first, float scale, int writeY)
{
  int g = blockIdx.x * blockDim.x + threadIdx.x;
  int r = g >> 4, lane = g & 15;
  if (r >= PAIR) return;
  const int* ptr; const uint2* colw; const float4* X; int rr;
  if (r < NU) { ptr = ptr_u; colw = colw_u; X = (const float4*)Xi_in; rr = r; }
  else        { ptr = ptr_i; colw = colw_i; X = (const float4*)Xu_in; rr = r - NU; }
  int b = ptr[rr], e2 = ptr[rr + 1];
  float4 a = make_float4(0.f, 0.f, 0.f, 0.f);
  int k = b;
  for (; k + 1 < e2; k += 2) {
    uint2 cw0 = colw[k];
    uint2 cw1 = colw[k + 1];
    float4 x0 = X[(size_t)cw0.x * 16 + lane];
    float4 x1 = X[(size_t)cw1.x * 16 + lane];
    float w0 = __uint_as_float(cw0.y), w1 = __uint_as_float(cw1.y);
    a.x += w0 * x0.x; a.y += w0 * x0.y; a.z += w0 * x0.z; a.w += w0 * x0.w;
    a.x += w1 * x1.x; a.y += w1 * x1.y; a.z += w1 * x1.z; a.w += w1 * x1.w;
  }
  if (k < e2) {
    uint2 cw = colw[k];
    float wk = __uint_as_float(cw.y);
    float4 x = X[(size_t)cw.x * 16 + lane];
    a.x += wk * x.x; a.y += wk * x.y; a.z += wk * x.z; a.w += wk * x.w;
  }
  if (writeY) ((float4*)Y)[r * 16 + lane] = a;
  if (acc) {
    float4 v;
    if (first) v = a;
    else {
      v = ((const float4*)acc)[r * 16 + lane];
      v.x += a.x; v.y += a.y; v.z += a.z; v.w += a.w;
    }
    v.x *= scale; v.y *= scale; v.z *= scale; v.w *= scale;
    ((float4*)acc)[r * 16 + lane] = v;
  }
}

// ---------------------------------------------------------------------------
// Combined two-sided noise + layer-mean:
//   v = S[r] + EPS * l2norm(S[perm-row]);
//   if writeO: O[r] = v;   acc = (first ? v : acc+v) * scale
// With writeO=0 & first=1 & scale=1, acc itself becomes the chain state (=v).
// ---------------------------------------------------------------------------
__global__ void k_noise2(const float* __restrict__ S, const int* __restrict__ perm,
                         float* __restrict__ O, float* __restrict__ acc,
                         int first, float scale, int writeO)
{
  int g = blockIdx.x * blockDim.x + threadIdx.x;
  int r = g >> 4, lane = g & 15;
  if (r >= PAIR) return;
  int pr = (r < NU) ? perm[r] : NU + perm[r];
  float4 z = ((const float4*)S)[(size_t)pr * 16 + lane];
  float ss = z.x * z.x + z.y * z.y + z.z * z.z + z.w * z.w;
#pragma unroll
  for (int m = 1; m < 16; m <<= 1) ss += __shfl_xor(ss, m);
  float coef = EPSV / fmaxf(sqrtf(ss), 1e-12f);
  float4 v = ((const float4*)S)[(size_t)r * 16 + lane];
  v.x += coef * z.x; v.y += coef * z.y; v.z += coef * z.z; v.w += coef * z.w;
  if (writeO) ((float4*)O)[r * 16 + lane] = v;
  float4 a;
  if (first) a = v;
  else {
    a = ((const float4*)acc)[r * 16 + lane];
    a.x += v.x; a.y += v.y; a.z += v.z; a.w += v.w;
  }
  a.x *= scale; a.y *= scale; a.z *= scale; a.w *= scale;
  ((float4*)acc)[r * 16 + lane] = a;
}

// ---------------------------------------------------------------------------
// Batched permutation sort (12 sorts, 2 stable-sort rounds).
// genkeys+hist fused; round-0 payload (iota) == pos array, so round 0 skips
// the val store and round 1 reads round-0's pos array as its payload.
// ---------------------------------------------------------------------------
__global__ void k_genhist(SortKeys sk, uint32_t* __restrict__ keys, int* __restrict__ hist)
{
  int gid = blockIdx.x * blockDim.x + threadIdx.x;
  if (gid >= TOTSORT) return;
  int r, local; regionOf(gid, r, local);
  uint32_t o0, o1;
  tf2x32(sk.a[r], sk.b[r], 0u, (uint32_t)local, o0, o1);
  uint32_t kk = o0 ^ o1;
  keys[gid] = kk;
  atomicAdd(&hist[r * NBUCK + (kk >> 16)], 1);
}

// valsIn==nullptr -> payload is the local iota; valO==nullptr -> skip val store.
__global__ void k_scatter_all(const uint32_t* __restrict__ keys,
                              const int* __restrict__ valsIn,
                              int* __restrict__ cursor,
                              uint32_t* __restrict__ keyO, int* __restrict__ valO,
                              int* __restrict__ posO)
{
  int gid = blockIdx.x * blockDim.x + threadIdx.x;
  if (gid >= TOTSORT) return;
  int r, local; regionOf(gid, r, local);
  uint32_t k = keys[gid];
  int p = atomicAdd(&cursor[r * NBUCK + (k >> 16)], 1);
  keyO[p] = k;
  if (valO) valO[p] = valsIn ? valsIn[gid] : local;
  posO[p] = local;
}

// per-bucket insertion sort by (key, pos) -> exactly JAX's stable sort_key_val
__global__ void k_fixup(const int* __restrict__ offs, uint32_t* __restrict__ keyO,
                        int* __restrict__ valO, int* __restrict__ posO)
{
  int b = blockIdx.x * blockDim.x + threadIdx.x;
  if (b >= NBALL) return;
  int s0 = offs[b], e0 = offs[b + 1];
  for (int i = s0 + 1; i < e0; ++i) {
    uint32_t k = keyO[i]; int p = posO[i];
    int v = valO ? valO[i] : 0;
    int j = i - 1;
    while (j >= s0 && (keyO[j] > k || (keyO[j] == k && posO[j] > p))) {
      keyO[j + 1] = keyO[j]; posO[j + 1] = posO[j];
      if (valO) valO[j + 1] = valO[j];
      --j;
    }
    keyO[j + 1] = k; posO[j + 1] = p;
    if (valO) valO[j + 1] = v;
  }
}

// ---------------------------------------------------------------------------
extern "C" void kernel_launch(void* const* d_in, const int* in_sizes, int n_in,
                              void* d_out, int out_size, void* d_ws, size_t ws_size,
                              hipStream_t stream)
{
  const int*   u_id = (const int*)d_in[0];
  const int*   i_id = (const int*)d_in[1];
  const int*   T    = (const int*)d_in[2];
  const float* beta = (const float*)d_in[3];
  const float* UE   = (const float*)d_in[4];
  const float* IE   = (const float*)d_in[5];
  const float* W0   = (const float*)d_in[6];
  const float* W1   = (const float*)d_in[7];
  (void)in_sizes; (void)n_in; (void)out_size; (void)ws_size;

  float* out    = (float*)d_out;
  float* accCln = out;                                 // [PAIR,64] (ufw;ifw)
  float* accP0  = out + (size_t)PAIR * DD;             // [PAIR,64] (up1;ip1)
  float* accP1  = out + 2ull * PAIR * DD;              // [PAIR,64] (up2;ip2)

  // --- workspace ------------------------------------------------------------
  char* wp = (char*)d_ws;
  auto carve = [&](size_t bytes) -> char* {
    char* r = wp; wp += (bytes + 255) & ~(size_t)255; return r;
  };
  int*   ptr_u    = (int*)  carve(4ull * (NU + 1));
  int*   cnt_u    = (int*)  carve(4ull * NU);
  int*   cur_u    = (int*)  carve(4ull * NU);
  int*   ptr_i    = (int*)  carve(4ull * (NI + 1));
  int*   cnt_i    = (int*)  carve(4ull * NI);
  int*   cur_i    = (int*)  carve(4ull * NI);
  uint2* colw_u   = (uint2*)carve(8ull * NE);
  uint2* colw_i   = (uint2*)carve(8ull * NE);
  int*   perms    = (int*)  carve(4ull * TOTSORT);
  int*   partials = (int*)  carve(4ull * 1025);

  const size_t PB = (size_t)PAIR * DD * 4;             // 76.8 MB per pair buffer
  char* uni = carve(2 * PB);                           // always 2 pair buffers

  float* P0 = (float*)uni;            // pair buffer 0 [PAIR,64]
  float* P1 = P0 + (size_t)PAIR * DD; // pair buffer 1

  // sort scratch overlays the pair buffers (phases strictly sequential)
  uint32_t* keysA = (uint32_t*)uni;              // TOTSORT
  uint32_t* keyB  = keysA + TOTSORT;             // TOTSORT
  int*      posA  = (int*)(keyB + TOTSORT);      // TOTSORT (round-0 pos==val)
  int*      posB  = posA + TOTSORT;              // TOTSORT (round-1 pos)
  int*      hist  = posB + TOTSORT;              // NBALL
  int*      offs  = hist + NBALL;                // NBALL+1
  int*      curs  = offs + NBALL + 1;            // NBALL

  // 1. CSR counts + offsets, then fused edge-weight + packed scatter
  hipMemsetAsync(cnt_u, 0, 4 * NU, stream);
  hipMemsetAsync(cnt_i, 0, 4 * NI, stream);
  k_count<<<CEILDIV(NE, 256), 256, 0, stream>>>(u_id, i_id, cnt_u, cnt_i);
  scan_ex(stream, cnt_u, NU, ptr_u, cur_u, partials, &ptr_u[NU]);
  scan_ex(stream, cnt_i, NI, ptr_i, cur_i, partials, &ptr_i[NI]);
  k_edgesc<<<CEILDIV(NE * 16, 256), 256, 0, stream>>>(u_id, i_id, T, beta, UE, IE,
                                                      W0, W1, cur_u, cur_i,
                                                      colw_u, colw_i);

  // 2. all 12 permutations, batched into 2 stable-sort stages
  SortKeys sk0, sk1;
  for (int p = 0; p < 2; ++p) {
    K2 base = {0u, (uint32_t)(p + 1)};                 // jax.random.key(p+1)
    for (int l = 0; l < 3; ++l) {
      K2 kl = h_tf(base, 0u, (uint32_t)l);             // fold_in(base, l)
      K2 kk[2] = { h_tf(kl, 0u, 0u), h_tf(kl, 0u, 1u) };  // split -> ku, ki
      for (int q = 0; q < 2; ++q) {
        int r = (p * 3 + l) * 2 + q;
        K2 kperm = kk[q];
        K2 knext = h_tf(kperm, 0u, 0u);                // split inside permutation
        K2 sub0  = h_tf(kperm, 0u, 1u);
        K2 sub1  = h_tf(knext, 0u, 1u);
        sk0.a[r] = sub0.a; sk0.b[r] = sub0.b;
        sk1.a[r] = sub1.a; sk1.b[r] = sub1.b;
      }
    }
  }
  const int GS = CEILDIV(TOTSORT, 256), GF = CEILDIV(NBALL, 256);
  // round 0: payload = iota == pos -> only (key, pos) arrays
  hipMemsetAsync(hist, 0, 4ull * NBALL, stream);
  k_genhist<<<GS, 256, 0, stream>>>(sk0, keysA, hist);
  scan_ex(stream, hist, NBALL, offs, curs, partials, &offs[NBALL]);
  k_scatter_all<<<GS, 256, 0, stream>>>(keysA, (const int*)nullptr, curs,
                                        keyB, (int*)nullptr, posA);
  k_fixup<<<GF, 256, 0, stream>>>(offs, keyB, (int*)nullptr, posA);
  // round 1: payload = round-0 result (posA) -> perms
  hipMemsetAsync(hist, 0, 4ull * NBALL, stream);
  k_genhist<<<GS, 256, 0, stream>>>(sk1, keysA, hist);
  scan_ex(stream, hist, NBALL, offs, curs, partials, &offs[NBALL]);
  k_scatter_all<<<GS, 256, 0, stream>>>(keysA, posA, curs, keyB, perms, posB);
  k_fixup<<<GF, 256, 0, stream>>>(offs, keyB, perms, posB);

  // 3. propagation — 7 SpMMs, layer-1 shared via d_out-resident chain state.
  const int GP = CEILDIV(PAIR * 16, 256);
  const float THIRD = 1.0f / 3.0f;
  auto SPMM = [&](const float* in, float* Y, float* acc,
                  int first, float scale, int writeY) {
    k_spmm2<<<GP, 256, 0, stream>>>(ptr_u, colw_u, in + (size_t)NU * DD,
                                    ptr_i, colw_i, in,
                                    Y, acc, first, scale, writeY);
  };
  auto SPMM0 = [&]() {  // layer-1 from embeddings: u gathers IE, i gathers UE
    k_spmm2<<<GP, 256, 0, stream>>>(ptr_u, colw_u, IE, ptr_i, colw_i, UE,
                                    P0, accCln, 1, 1.0f, 1);
  };
  auto NOISE = [&](const float* S, int pass, int layer, float* O, float* acc,
                   int first, float scale, int writeO) {
    k_noise2<<<GP, 256, 0, stream>>>(S, perms + (size_t)(pass * 3 + layer) * PAIR,
                                     O, acc, first, scale, writeO);
  };

  // L1 raw (shared by all 3 passes) -> P0; clean acc init
  SPMM0();
  // clean layers 2,3
  SPMM(P0, P1, accCln, 0, 1.0f, 1);
  SPMM(P1, nullptr, accCln, 0, THIRD, 0);
  // layer-1 noise for both passes; acc doubles as the chain state (acc = O1)
  NOISE(P0, 0, 0, nullptr, accP0, 1, 1.0f, 0);
  NOISE(P0, 1, 0, nullptr, accP1, 1, 1.0f, 0);
  // pass 0: chain lives in accP0 -> P0 -> ...
  SPMM(accP0, P1, nullptr, 0, 1.0f, 1);          // layer 2 spmm
  NOISE(P1, 0, 1, P0, accP0, 0, 1.0f, 1);        // chain=P0=O2, accP0=O1+O2
  SPMM(P0, P1, nullptr, 0, 1.0f, 1);             // layer 3 spmm
  NOISE(P1, 0, 2, nullptr, accP0, 0, THIRD, 0);  // accP0=(O1+O2+O3)/3
  // pass 1
  SPMM(accP1, P1, nullptr, 0, 1.0f, 1);
  NOISE(P1, 1, 1, P0, accP1, 0, 1.0f, 1);
  SPMM(P0, P1, nullptr, 0, 1.0f, 1);
  NOISE(P1, 1, 2, nullptr, accP1, 0, THIRD, 0);
}